// Round 3
// baseline (181.408 us; speedup 1.0000x reference)
//
#include <hip/hip_runtime.h>

// AnalyticalBoundedLineAttractor — exact linear-regime stepping via Taylor
// recurrence:
//   z = Wx + b; m_dt = (z>0)?dt:0
//   w1 = m_dt*z - dt*x;  wk = (m_dt*(W w) - dt*w)/k;  x+ = x + sum wk
// ||Z|| <= dt*(||W||_2+1) ~ 0.15 -> K=3 terms, local truncation ~2e-5/step,
// accumulated ~6e-3 (threshold 7.7e-2; non-expansive dynamics, no blowup).
//
// R2: two chains per wave + Wr register pinning. Post-mortem history:
//   R0 (readlane, 1 chain): 65.5 us dispatch = ~520 cyc/matvec vs 260 cyc
//     issue bound. VGPR_Count=48 < 64 proves the compiler did NOT keep
//     Wr[64] resident — it rematerialized W loads inside the t-loop, so
//     every matvec pays L1/L2 latency. Also readlane->SGPR->fma wait states.
//   R1 (LDS broadcast): 124 us — ds_write->lgkmcnt(0)->ds_read round-trip
//     (~+470 cyc/matvec) is WORSE than both. Reverted.
//   R2 therefore: (a) interleave two independent batch chains in one wave —
//     chain B's instructions fill chain A's stall slots (issue bound for a
//     double-matvec = 512 cyc ~= R0's single-matvec latency, so per-chain
//     cost ~halves); (b) empty asm "+v" pins on Wr inside the loop forbid
//     rematerialization (0 instructions, forces VGPR residency; both chains
//     share one Wr copy). Per-chain FMA order is UNCHANGED -> absmax stays
//     bitwise 0.015625.

#define DT_F 0.05f
#define T_STEPS 100
#define DD 64
#define KT 3      // Taylor terms w_1..w_KT
#define BATCH_MAX 256

// Interleaved double matvec: rA = W·wA, rB = W·wB. Lane i holds row i of W.
// 128 independent readlanes + 128 FMAs on 8 accumulators; the two streams
// have no cross-dependencies, so every stall slot of one is fillable by the
// other.
__device__ __forceinline__ void matvec2(const float (&Wr)[DD],
                                        const float wA, const float wB,
                                        float& rA, float& rB) {
    const int ia = __float_as_int(wA);
    const int ib = __float_as_int(wB);
    float a0 = 0.f, a1 = 0.f, a2 = 0.f, a3 = 0.f;
    float c0 = 0.f, c1 = 0.f, c2 = 0.f, c3 = 0.f;
#pragma unroll
    for (int j = 0; j < DD; j += 4) {
        const float sa0 = __int_as_float(__builtin_amdgcn_readlane(ia, j + 0));
        const float sa1 = __int_as_float(__builtin_amdgcn_readlane(ia, j + 1));
        const float sa2 = __int_as_float(__builtin_amdgcn_readlane(ia, j + 2));
        const float sa3 = __int_as_float(__builtin_amdgcn_readlane(ia, j + 3));
        const float sb0 = __int_as_float(__builtin_amdgcn_readlane(ib, j + 0));
        const float sb1 = __int_as_float(__builtin_amdgcn_readlane(ib, j + 1));
        const float sb2 = __int_as_float(__builtin_amdgcn_readlane(ib, j + 2));
        const float sb3 = __int_as_float(__builtin_amdgcn_readlane(ib, j + 3));
        a0 = fmaf(Wr[j + 0], sa0, a0);
        c0 = fmaf(Wr[j + 0], sb0, c0);
        a1 = fmaf(Wr[j + 1], sa1, a1);
        c1 = fmaf(Wr[j + 1], sb1, c1);
        a2 = fmaf(Wr[j + 2], sa2, a2);
        c2 = fmaf(Wr[j + 2], sb2, c2);
        a3 = fmaf(Wr[j + 3], sa3, a3);
        c3 = fmaf(Wr[j + 3], sb3, c3);
    }
    rA = (a0 + a1) + (a2 + a3);
    rB = (c0 + c1) + (c2 + c3);
}

__global__ __launch_bounds__(64, 1)
void abla_kernel(const float* __restrict__ x0,
                 const float* __restrict__ W,
                 const float* __restrict__ bvec,
                 float* __restrict__ out) {
    const int bA = blockIdx.x * 2;
    const int bB = bA + 1;
    const int lane = threadIdx.x;

    // Lane i caches row i of W (natural order). Pinned to VGPRs below.
    float Wr[DD];
#pragma unroll
    for (int j = 0; j < DD; j += 4) {
        const float4 w4 = *reinterpret_cast<const float4*>(W + lane * DD + j);
        Wr[j + 0] = w4.x; Wr[j + 1] = w4.y; Wr[j + 2] = w4.z; Wr[j + 3] = w4.w;
    }
    const float bi = bvec[lane];
    float xA = x0[bA * DD + lane];
    float xB = x0[bB * DD + lane];
    float* outA = out + (size_t)bA * T_STEPS * DD + lane;
    float* outB = out + (size_t)bB * T_STEPS * DD + lane;

    for (int t = 0; t < T_STEPS; ++t) {
        // Forbid rematerialization of the W row: force each element to be
        // VGPR-resident here. Emits no instructions.
#pragma unroll
        for (int j = 0; j < DD; ++j) asm volatile("" : "+v"(Wr[j]));

        // Trajectory stores the state BEFORE the update (off critical path).
        outA[(size_t)t * DD] = xA;
        outB[(size_t)t * DD] = xB;

        // term 1: z = Wx + b gives the regime mask
        float zA, zB;
        matvec2(Wr, xA, xB, zA, zB);
        zA += bi; zB += bi;
        const float mA = (zA > 0.f) ? DT_F : 0.f;
        const float mB = (zB > 0.f) ? DT_F : 0.f;
        float wA = mA * zA - DT_F * xA;
        float wB = mB * zB - DT_F * xB;
        float yA = xA + wA;
        float yB = xB + wB;

        // terms 2..KT
#pragma unroll
        for (int k = 2; k <= KT; ++k) {
            float vA, vB;
            matvec2(Wr, wA, wB, vA, vB);
            wA = (mA * vA - DT_F * wA) * (1.0f / (float)k);
            wB = (mB * vB - DT_F * wB) * (1.0f / (float)k);
            yA += wA;
            yB += wB;
        }
        xA = yA;
        xB = yB;
    }
}

extern "C" void kernel_launch(void* const* d_in, const int* in_sizes, int n_in,
                              void* d_out, int out_size, void* d_ws, size_t ws_size,
                              hipStream_t stream) {
    const float* x0 = (const float*)d_in[0];   // (256, 64) f32
    const float* W  = (const float*)d_in[1];   // (64, 64)  f32
    const float* b  = (const float*)d_in[2];   // (64,)     f32
    float* out = (float*)d_out;                // (256, 100, 64) f32

    // Problem shape is fixed (batch=256, dim=64). Derive batch from
    // in_sizes[0] when it is a plausible element count; clamp otherwise so a
    // bytes-vs-elements unit mismatch can never launch an OOB grid.
    int batch = in_sizes[0] / DD;
    if (batch <= 0 || batch > BATCH_MAX) batch = BATCH_MAX;
    const int pairs = (batch + 1) / 2;         // 128 waves, 2 chains each
    abla_kernel<<<pairs, DD, 0, stream>>>(x0, W, b, out);
}